// Round 4
// baseline (905.162 us; speedup 1.0000x reference)
//
#include <hip/hip_runtime.h>
#include <hip/hip_bf16.h>

typedef unsigned short u16;
typedef unsigned int u32;
typedef float f32x4 __attribute__((ext_vector_type(4)));
typedef short bf16x8 __attribute__((ext_vector_type(8)));   // 8 bf16 carried as shorts (guide §3)
typedef u32 u32x4 __attribute__((ext_vector_type(4)));

__device__ __forceinline__ u16 f2bf(float f) {
  u32 x = __builtin_bit_cast(u32, f);
  x += 0x7fffu + ((x >> 16) & 1u);   // RNE (inputs finite)
  return (u16)(x >> 16);
}
__device__ __forceinline__ float bf2f(u16 h) {
  return __builtin_bit_cast(float, (u32)h << 16);
}
__device__ __forceinline__ u32 pk2(float a, float b) {
  return (u32)f2bf(a) | ((u32)f2bf(b) << 16);
}
__device__ __forceinline__ f32x4 fzero4() {
  f32x4 v; v[0] = 0.f; v[1] = 0.f; v[2] = 0.f; v[3] = 0.f; return v;
}
#define MFMA16(a, b, c) __builtin_amdgcn_mfma_f32_16x16x32_bf16(a, b, c, 0, 0, 0)

// ---------------------------------------------------------------------------
// GEMM: C[M=grid.y*128][N] = A[.][K] * B[K][N], MFMA bf16, f32 or bf16 A,
// B always f32 (converted in staging), C written bf16 or f32.
// 128x128 tile, BK=64, 4 waves (2x2), per-wave 64x64 = 4x4 16x16 frags.
// LDS: As[row][k] and Bs[n][k] (B transposed during staging), XOR-swizzled.
// ---------------------------------------------------------------------------
template<int N, int K, bool ABF16, bool OUTBF16>
__global__ void __launch_bounds__(256, 2)
gemm_kernel(const void* __restrict__ Av, const float* __restrict__ B,
            void* __restrict__ Cv) {
  const int tid = threadIdx.x;
  const int lane = tid & 63;
  const int lo = lane & 15, hi = lane >> 4;
  const int wv = tid >> 6;
  const int wr = wv >> 1, wc = wv & 1;
  const int bm0 = blockIdx.y * 128, bn0 = blockIdx.x * 128;

  __shared__ __attribute__((aligned(16))) u16 As[128 * 64];
  __shared__ __attribute__((aligned(16))) u16 Bs[128 * 64];

  f32x4 acc[4][4];
#pragma unroll
  for (int i = 0; i < 4; ++i)
#pragma unroll
    for (int j = 0; j < 4; ++j) acc[i][j] = fzero4();

  const int bn = tid & 127;   // B: column-per-thread
  const int bkh = tid >> 7;   // k half (32 rows each)

  for (int k0 = 0; k0 < K; k0 += 64) {
    // ---- global loads into registers
    float bcol[32];
#pragma unroll
    for (int kk = 0; kk < 32; ++kk)
      bcol[kk] = B[(size_t)(k0 + bkh * 32 + kk) * N + bn0 + bn];

    f32x4 areg[8];
    u32x4 aregb[4];
    if constexpr (ABF16) {
      const u16* Ab = (const u16*)Av;
#pragma unroll
      for (int rr = 0; rr < 2; ++rr) {
        int row = rr * 64 + (tid >> 2);
        int c16 = (tid & 3) * 16;
        const u16* p = Ab + (size_t)(bm0 + row) * K + k0 + c16;
        aregb[rr * 2 + 0] = *(const u32x4*)(p);
        aregb[rr * 2 + 1] = *(const u32x4*)(p + 8);
      }
    } else {
      const float* Af = (const float*)Av;
#pragma unroll
      for (int rr = 0; rr < 4; ++rr) {
        int row = rr * 32 + (tid >> 3);
        int c8 = (tid & 7) * 8;
        const float* p = Af + (size_t)(bm0 + row) * K + k0 + c8;
        areg[rr * 2 + 0] = *(const f32x4*)(p);
        areg[rr * 2 + 1] = *(const f32x4*)(p + 4);
      }
    }

    __syncthreads();   // previous tile fully consumed

    // ---- LDS writes (bf16, swizzled)
#pragma unroll
    for (int c = 0; c < 4; ++c) {
      u32x4 w;
#pragma unroll
      for (int e = 0; e < 4; ++e)
        w[e] = pk2(bcol[c * 8 + e * 2], bcol[c * 8 + e * 2 + 1]);
      int col = bkh * 32 + c * 8;
      *(u32x4*)&Bs[bn * 64 + (col ^ ((bn & 7) << 3))] = w;
    }
    if constexpr (ABF16) {
#pragma unroll
      for (int rr = 0; rr < 2; ++rr) {
        int row = rr * 64 + (tid >> 2);
        int c16 = (tid & 3) * 16;
        *(u32x4*)&As[row * 64 + ((c16 + 0) ^ ((row & 7) << 3))] = aregb[rr * 2 + 0];
        *(u32x4*)&As[row * 64 + ((c16 + 8) ^ ((row & 7) << 3))] = aregb[rr * 2 + 1];
      }
    } else {
#pragma unroll
      for (int rr = 0; rr < 4; ++rr) {
        int row = rr * 32 + (tid >> 3);
        int c8 = (tid & 7) * 8;
        u32x4 w;
        w[0] = pk2(areg[rr * 2 + 0][0], areg[rr * 2 + 0][1]);
        w[1] = pk2(areg[rr * 2 + 0][2], areg[rr * 2 + 0][3]);
        w[2] = pk2(areg[rr * 2 + 1][0], areg[rr * 2 + 1][1]);
        w[3] = pk2(areg[rr * 2 + 1][2], areg[rr * 2 + 1][3]);
        *(u32x4*)&As[row * 64 + (c8 ^ ((row & 7) << 3))] = w;
      }
    }

    __syncthreads();

    // ---- MFMA: 2 k-steps of 32
#pragma unroll
    for (int ks = 0; ks < 2; ++ks) {
      bf16x8 a[4], b[4];
#pragma unroll
      for (int mf = 0; mf < 4; ++mf) {
        int r = wr * 64 + mf * 16 + lo;
        a[mf] = __builtin_bit_cast(bf16x8,
            *(const u32x4*)&As[r * 64 + ((ks * 32 + hi * 8) ^ ((r & 7) << 3))]);
      }
#pragma unroll
      for (int nf = 0; nf < 4; ++nf) {
        int n = wc * 64 + nf * 16 + lo;
        b[nf] = __builtin_bit_cast(bf16x8,
            *(const u32x4*)&Bs[n * 64 + ((ks * 32 + hi * 8) ^ ((n & 7) << 3))]);
      }
#pragma unroll
      for (int mf = 0; mf < 4; ++mf)
#pragma unroll
        for (int nf = 0; nf < 4; ++nf)
          acc[mf][nf] = MFMA16(a[mf], b[nf], acc[mf][nf]);
    }
  }

  // ---- epilogue: C row = (lane>>4)*4 + reg, col = lane&15 (verified layout)
#pragma unroll
  for (int mf = 0; mf < 4; ++mf)
#pragma unroll
    for (int nf = 0; nf < 4; ++nf)
#pragma unroll
      for (int r = 0; r < 4; ++r) {
        int row = bm0 + wr * 64 + mf * 16 + hi * 4 + r;
        int col = bn0 + wc * 64 + nf * 16 + lo;
        if constexpr (OUTBF16)
          ((u16*)Cv)[(size_t)row * N + col] = f2bf(acc[mf][nf][r]);
        else
          ((float*)Cv)[(size_t)row * N + col] = acc[mf][nf][r];
      }
}

// ---------------------------------------------------------------------------
// RoPE, in place on bf16 qkv (q: cols 0..4095, k: cols 4096..5119).
// Split-half: out[j] = x[j] cos - x[j+64] sin ; out[j+64] = x[j+64] cos + x[j] sin
// ---------------------------------------------------------------------------
__global__ void __launch_bounds__(256)
rope_kernel(u16* __restrict__ qkv, const int* __restrict__ positions) {
  const int t = blockIdx.y;
  const int pid = blockIdx.x * 256 + threadIdx.x;  // 0..2559 : 40 heads x 64 pairs
  const int head = pid >> 6;
  const int j = pid & 63;
  const int base = (head < 32) ? head * 128 : 4096 + (head - 32) * 128;
  const float pos = (float)positions[t];
  // freq = 10000^{-j/64} = 2^{-j*log2(1e4)/64}
  const float freq = exp2f((float)j * (-13.287712379549449f / 64.f));
  float sn, cs;
  sincosf(pos * freq, &sn, &cs);
  u16* p1 = qkv + (size_t)t * 6144 + base + j;
  u16* p2 = p1 + 64;
  const float x1 = bf2f(*p1), x2 = bf2f(*p2);
  *p1 = f2bf(x1 * cs - x2 * sn);
  *p2 = f2bf(x2 * cs + x1 * sn);
}

// ---------------------------------------------------------------------------
// Flash attention, causal, GQA group 4. Block = (q-tile of 64) x head.
// 4 waves x 16 q-rows. K/V tiles (64 rows) staged in LDS each iteration.
// S = Q K^T via mfma(Qfrag, K-as-Bfrag); P routed through wave-private LDS
// to become the PV A-fragment; V stored transposed (Vs[d][kv]) for B-frags.
// ---------------------------------------------------------------------------
__global__ void __launch_bounds__(256, 2)
attn_kernel(const u16* __restrict__ qkv, u16* __restrict__ ctx) {
  const int tid = threadIdx.x;
  const int lane = tid & 63;
  const int lo = lane & 15, hi = lane >> 4;
  const int wv = tid >> 6;
  const int qt = blockIdx.x;
  const int h = blockIdx.y;
  const int kvh = h >> 2;

  __shared__ __attribute__((aligned(16))) u16 Ks[64 * 128];
  __shared__ __attribute__((aligned(16))) u16 Vs[128 * 64];
  __shared__ __attribute__((aligned(16))) u16 Ps[4][16 * 64];

  // Q fragments: lane covers Q row (qt*64 + wv*16 + lo), dims ks*32+hi*8 ..+7
  bf16x8 qf[4];
  {
    const u16* qp = qkv + (size_t)(qt * 64 + wv * 16 + lo) * 6144 + h * 128;
#pragma unroll
    for (int ks = 0; ks < 4; ++ks)
      qf[ks] = __builtin_bit_cast(bf16x8, *(const u32x4*)(qp + ks * 32 + hi * 8));
  }

  f32x4 acc_o[8];
#pragma unroll
  for (int i = 0; i < 8; ++i) acc_o[i] = fzero4();
  float m_run[4] = {-1e30f, -1e30f, -1e30f, -1e30f};
  float l_run[4] = {0.f, 0.f, 0.f, 0.f};
  const float scale = 0.08838834764831845f;  // 128^-0.5

  const int krow = tid >> 2;        // K staging: kv row 0..63
  const int kcb = (tid & 3) * 32;   // col base
  const int vd = tid & 127;         // V staging: head-dim column
  const int vkh = tid >> 7;         // kv half

  for (int kt = 0; kt <= qt; ++kt) {
    // ---- global loads
    u32x4 kreg[4];
    {
      const u16* kp = qkv + (size_t)(kt * 64 + krow) * 6144 + 4096 + kvh * 128 + kcb;
#pragma unroll
      for (int i = 0; i < 4; ++i) kreg[i] = *(const u32x4*)(kp + i * 8);
    }
    u16 vreg[32];
    {
      const u16* vp = qkv + (size_t)(kt * 64 + vkh * 32) * 6144 + 5120 + kvh * 128 + vd;
#pragma unroll
      for (int kk = 0; kk < 32; ++kk) vreg[kk] = vp[(size_t)kk * 6144];
    }

    __syncthreads();

    // ---- LDS writes
#pragma unroll
    for (int i = 0; i < 4; ++i) {
      int col = kcb + i * 8;
      *(u32x4*)&Ks[krow * 128 + (col ^ ((krow & 7) << 3))] = kreg[i];
    }
#pragma unroll
    for (int c = 0; c < 4; ++c) {
      u32x4 w;
#pragma unroll
      for (int e = 0; e < 4; ++e)
        w[e] = (u32)vreg[c * 8 + e * 2] | ((u32)vreg[c * 8 + e * 2 + 1] << 16);
      int col = vkh * 32 + c * 8;
      *(u32x4*)&Vs[vd * 64 + (col ^ ((vd & 7) << 3))] = w;
    }

    __syncthreads();

    // ---- S = Q K^T  (16 x 64 per wave)
    f32x4 s[4];
#pragma unroll
    for (int nf = 0; nf < 4; ++nf) s[nf] = fzero4();
#pragma unroll
    for (int nf = 0; nf < 4; ++nf) {
      int r = nf * 16 + lo;
#pragma unroll
      for (int ks = 0; ks < 4; ++ks) {
        bf16x8 kf = __builtin_bit_cast(bf16x8,
            *(const u32x4*)&Ks[r * 128 + ((ks * 32 + hi * 8) ^ ((r & 7) << 3))]);
        s[nf] = MFMA16(qf[ks], kf, s[nf]);
      }
    }

    // ---- online softmax (rows = hi*4+r, cols = nf*16+lo)
    const bool diag = (kt == qt);
    float p[4][4];
    float mt[4] = {-1e30f, -1e30f, -1e30f, -1e30f};
#pragma unroll
    for (int nf = 0; nf < 4; ++nf)
#pragma unroll
      for (int r = 0; r < 4; ++r) {
        float v = s[nf][r] * scale;
        if (diag && (nf * 16 + lo > wv * 16 + hi * 4 + r)) v = -1e30f;
        p[nf][r] = v;
        mt[r] = fmaxf(mt[r], v);
      }
#pragma unroll
    for (int m = 1; m <= 8; m <<= 1)
#pragma unroll
      for (int r = 0; r < 4; ++r)
        mt[r] = fmaxf(mt[r], __shfl_xor(mt[r], m));
    float alpha[4], rs[4];
#pragma unroll
    for (int r = 0; r < 4; ++r) {
      float mn = fmaxf(m_run[r], mt[r]);
      alpha[r] = __expf(m_run[r] - mn);
      m_run[r] = mn;
      rs[r] = 0.f;
    }
#pragma unroll
    for (int nf = 0; nf < 4; ++nf)
#pragma unroll
      for (int r = 0; r < 4; ++r) {
        p[nf][r] = __expf(p[nf][r] - m_run[r]);
        rs[r] += p[nf][r];
      }
#pragma unroll
    for (int m = 1; m <= 8; m <<= 1)
#pragma unroll
      for (int r = 0; r < 4; ++r)
        rs[r] += __shfl_xor(rs[r], m);
#pragma unroll
    for (int r = 0; r < 4; ++r)
      l_run[r] = l_run[r] * alpha[r] + rs[r];
#pragma unroll
    for (int df = 0; df < 8; ++df)
#pragma unroll
      for (int r = 0; r < 4; ++r)
        acc_o[df][r] *= alpha[r];

    // ---- P -> wave-private LDS (re-layout C-frag to A-frag)
#pragma unroll
    for (int nf = 0; nf < 4; ++nf)
#pragma unroll
      for (int r = 0; r < 4; ++r) {
        int row = hi * 4 + r;
        int col = nf * 16 + lo;
        Ps[wv][row * 64 + (col ^ ((row & 7) << 3))] = f2bf(p[nf][r]);
      }

    // ---- O += P V
    bf16x8 pa[2];
#pragma unroll
    for (int ks2 = 0; ks2 < 2; ++ks2)
      pa[ks2] = __builtin_bit_cast(bf16x8,
          *(const u32x4*)&Ps[wv][lo * 64 + ((ks2 * 32 + hi * 8) ^ ((lo & 7) << 3))]);
#pragma unroll
    for (int df = 0; df < 8; ++df) {
      int r = df * 16 + lo;
#pragma unroll
      for (int ks2 = 0; ks2 < 2; ++ks2) {
        bf16x8 vf = __builtin_bit_cast(bf16x8,
            *(const u32x4*)&Vs[r * 64 + ((ks2 * 32 + hi * 8) ^ ((r & 7) << 3))]);
        acc_o[df] = MFMA16(pa[ks2], vf, acc_o[df]);
      }
    }
  }

  // ---- normalize + write ctx (bf16)
#pragma unroll
  for (int df = 0; df < 8; ++df)
#pragma unroll
    for (int r = 0; r < 4; ++r) {
      int row = qt * 64 + wv * 16 + hi * 4 + r;
      int col = h * 128 + df * 16 + lo;
      ctx[(size_t)row * 4096 + col] = f2bf(acc_o[df][r] / l_run[r]);
    }
}

// ---------------------------------------------------------------------------
extern "C" void kernel_launch(void* const* d_in, const int* in_sizes, int n_in,
                              void* d_out, int out_size, void* d_ws, size_t ws_size,
                              hipStream_t stream) {
  const float* hidden    = (const float*)d_in[0];  // [2048][4096]
  const int* positions   = (const int*)d_in[1];    // [2048]
  const float* w_qkv     = (const float*)d_in[2];  // [4096][6144]
  const float* w_o       = (const float*)d_in[3];  // [4096][4096]

  u16* qkv = (u16*)d_out;   // 2048x6144 bf16 scratch (25.2MB < 33.5MB out buf)
  u16* ctx = (u16*)d_ws;    // 2048x4096 bf16 (16.8MB of workspace)
  float* out = (float*)d_out;

  // 1) qkv = hidden @ w_qkv   (bf16 out)
  gemm_kernel<6144, 4096, false, true>
      <<<dim3(48, 16), 256, 0, stream>>>(hidden, w_qkv, qkv);
  // 2) RoPE on q,k in place
  rope_kernel<<<dim3(10, 2048), 256, 0, stream>>>(qkv, positions);
  // 3) ctx = causal GQA attention
  attn_kernel<<<dim3(32, 32), 256, 0, stream>>>(qkv, ctx);
  // 4) out = ctx @ w_o   (f32 out, overwrites the qkv scratch)
  gemm_kernel<4096, 4096, true, false>
      <<<dim3(32, 16), 256, 0, stream>>>(ctx, w_o, out);
}

// Round 5
// 853.191 us; speedup vs baseline: 1.0609x; 1.0609x over previous
//
#include <hip/hip_runtime.h>
#include <hip/hip_bf16.h>

typedef unsigned short u16;
typedef unsigned int u32;
typedef float f32x4 __attribute__((ext_vector_type(4)));
typedef short bf16x8 __attribute__((ext_vector_type(8)));
typedef u32 u32x4 __attribute__((ext_vector_type(4)));

__device__ __forceinline__ u16 f2bf(float f) {
  u32 x = __builtin_bit_cast(u32, f);
  x += 0x7fffu + ((x >> 16) & 1u);
  return (u16)(x >> 16);
}
__device__ __forceinline__ float bf2f(u16 h) {
  return __builtin_bit_cast(float, (u32)h << 16);
}
__device__ __forceinline__ u32 pk2(float a, float b) {
  return (u32)f2bf(a) | ((u32)f2bf(b) << 16);
}
__device__ __forceinline__ f32x4 fzero4() {
  f32x4 v; v[0] = 0.f; v[1] = 0.f; v[2] = 0.f; v[3] = 0.f; return v;
}
#define MFMA16(a, b, c) __builtin_amdgcn_mfma_f32_16x16x32_bf16(a, b, c, 0, 0, 0)

// ---------------------------------------------------------------------------
// GEMM: C[M][N] = A[M][K] * B[K][N]. 128x128 tile, BK=64, 4 waves (2x2).
// B staged with coalesced f32x4 row loads + packed u32 transpose writes
// (was: 32 scalar strided loads -> latency-bound, VMEM inst 32->8/thread).
// ---------------------------------------------------------------------------
template<int N, int K, bool ABF16, bool OUTBF16>
__global__ void __launch_bounds__(256, 2)
gemm_kernel(const void* __restrict__ Av, const float* __restrict__ B,
            void* __restrict__ Cv) {
  const int tid = threadIdx.x;
  const int lane = tid & 63;
  const int lo = lane & 15, hi = lane >> 4;
  const int wv = tid >> 6;
  const int wr = wv >> 1, wc = wv & 1;
  const int bm0 = blockIdx.y * 128, bn0 = blockIdx.x * 128;

  __shared__ __attribute__((aligned(16))) u16 As[128 * 64];
  __shared__ __attribute__((aligned(16))) u16 Bs[128 * 64];

  f32x4 acc[4][4];
#pragma unroll
  for (int i = 0; i < 4; ++i)
#pragma unroll
    for (int j = 0; j < 4; ++j) acc[i][j] = fzero4();

  // B staging map: pairs of k-rows, coalesced along n
  const int bkp = (tid >> 5) * 2;   // 0,2,..,14
  const int bnb = (tid & 31) * 4;   // n within tile

  for (int k0 = 0; k0 < K; k0 += 64) {
    // ---- global loads (coalesced)
    f32x4 brow0[4], brow1[4];
#pragma unroll
    for (int dr = 0; dr < 4; ++dr) {
      int k = dr * 16 + bkp;
      brow0[dr] = *(const f32x4*)&B[(size_t)(k0 + k) * N + bn0 + bnb];
      brow1[dr] = *(const f32x4*)&B[(size_t)(k0 + k + 1) * N + bn0 + bnb];
    }
    f32x4 areg[8];
    u32x4 aregb[4];
    if constexpr (ABF16) {
      const u16* Ab = (const u16*)Av;
#pragma unroll
      for (int rr = 0; rr < 2; ++rr) {
        int row = rr * 64 + (tid >> 2);
        int c16 = (tid & 3) * 16;
        const u16* p = Ab + (size_t)(bm0 + row) * K + k0 + c16;
        aregb[rr * 2 + 0] = *(const u32x4*)(p);
        aregb[rr * 2 + 1] = *(const u32x4*)(p + 8);
      }
    } else {
      const float* Af = (const float*)Av;
#pragma unroll
      for (int rr = 0; rr < 4; ++rr) {
        int row = rr * 32 + (tid >> 3);
        int c8 = (tid & 7) * 8;
        const float* p = Af + (size_t)(bm0 + row) * K + k0 + c8;
        areg[rr * 2 + 0] = *(const f32x4*)(p);
        areg[rr * 2 + 1] = *(const f32x4*)(p + 4);
      }
    }

    __syncthreads();

    // ---- B transpose-write: Bs[n][k], k-index XOR-swizzled by n&7
#pragma unroll
    for (int dr = 0; dr < 4; ++dr) {
      int k = dr * 16 + bkp;
#pragma unroll
      for (int i = 0; i < 4; ++i) {
        int n = bnb + i;
        *(u32*)&Bs[n * 64 + (k ^ ((n & 7) << 3))] = pk2(brow0[dr][i], brow1[dr][i]);
      }
    }
    if constexpr (ABF16) {
#pragma unroll
      for (int rr = 0; rr < 2; ++rr) {
        int row = rr * 64 + (tid >> 2);
        int c16 = (tid & 3) * 16;
        *(u32x4*)&As[row * 64 + ((c16 + 0) ^ ((row & 7) << 3))] = aregb[rr * 2 + 0];
        *(u32x4*)&As[row * 64 + ((c16 + 8) ^ ((row & 7) << 3))] = aregb[rr * 2 + 1];
      }
    } else {
#pragma unroll
      for (int rr = 0; rr < 4; ++rr) {
        int row = rr * 32 + (tid >> 3);
        int c8 = (tid & 7) * 8;
        u32x4 w;
        w[0] = pk2(areg[rr * 2 + 0][0], areg[rr * 2 + 0][1]);
        w[1] = pk2(areg[rr * 2 + 0][2], areg[rr * 2 + 0][3]);
        w[2] = pk2(areg[rr * 2 + 1][0], areg[rr * 2 + 1][1]);
        w[3] = pk2(areg[rr * 2 + 1][2], areg[rr * 2 + 1][3]);
        *(u32x4*)&As[row * 64 + (c8 ^ ((row & 7) << 3))] = w;
      }
    }

    __syncthreads();

#pragma unroll
    for (int ks = 0; ks < 2; ++ks) {
      bf16x8 a[4], b[4];
#pragma unroll
      for (int mf = 0; mf < 4; ++mf) {
        int r = wr * 64 + mf * 16 + lo;
        a[mf] = __builtin_bit_cast(bf16x8,
            *(const u32x4*)&As[r * 64 + ((ks * 32 + hi * 8) ^ ((r & 7) << 3))]);
      }
#pragma unroll
      for (int nf = 0; nf < 4; ++nf) {
        int n = wc * 64 + nf * 16 + lo;
        b[nf] = __builtin_bit_cast(bf16x8,
            *(const u32x4*)&Bs[n * 64 + ((ks * 32 + hi * 8) ^ ((n & 7) << 3))]);
      }
#pragma unroll
      for (int mf = 0; mf < 4; ++mf)
#pragma unroll
        for (int nf = 0; nf < 4; ++nf)
          acc[mf][nf] = MFMA16(a[mf], b[nf], acc[mf][nf]);
    }
  }

#pragma unroll
  for (int mf = 0; mf < 4; ++mf)
#pragma unroll
    for (int nf = 0; nf < 4; ++nf)
#pragma unroll
      for (int r = 0; r < 4; ++r) {
        int row = bm0 + wr * 64 + mf * 16 + hi * 4 + r;
        int col = bn0 + wc * 64 + nf * 16 + lo;
        if constexpr (OUTBF16)
          ((u16*)Cv)[(size_t)row * N + col] = f2bf(acc[mf][nf][r]);
        else
          ((float*)Cv)[(size_t)row * N + col] = acc[mf][nf][r];
      }
}

// ---------------------------------------------------------------------------
// RoPE (unchanged)
// ---------------------------------------------------------------------------
__global__ void __launch_bounds__(256)
rope_kernel(u16* __restrict__ qkv, const int* __restrict__ positions) {
  const int t = blockIdx.y;
  const int pid = blockIdx.x * 256 + threadIdx.x;
  const int head = pid >> 6;
  const int j = pid & 63;
  const int base = (head < 32) ? head * 128 : 4096 + (head - 32) * 128;
  const float pos = (float)positions[t];
  const float freq = exp2f((float)j * (-13.287712379549449f / 64.f));
  float sn, cs;
  sincosf(pos * freq, &sn, &cs);
  u16* p1 = qkv + (size_t)t * 6144 + base + j;
  u16* p2 = p1 + 64;
  const float x1 = bf2f(*p1), x2 = bf2f(*p2);
  *p1 = f2bf(x1 * cs - x2 * sn);
  *p2 = f2bf(x2 * cs + x1 * sn);
}

// ---------------------------------------------------------------------------
// Flash attention v2: QBLK=128 (4 waves x 32 q-rows), KVBLK=64.
// - K/V loaded as coalesced b128, V transposed into LDS via swizzled scatter
//   (VMEM inst/iter/thread 36 -> 8)
// - register prefetch of next K/V tile overlapped with current compute (T14)
// - big-qt blocks dispatched first (LPT balance for causal skew)
// Grid: (32 heads, 16 q-tiles).
// ---------------------------------------------------------------------------
__global__ void __launch_bounds__(256, 2)
attn_kernel(const u16* __restrict__ qkv, u16* __restrict__ ctx) {
  const int tid = threadIdx.x;
  const int lane = tid & 63;
  const int lo = lane & 15, hi = lane >> 4;
  const int wv = tid >> 6;
  const int h = blockIdx.x;
  const int qt = 15 - (int)blockIdx.y;   // big blocks first
  const int kvh = h >> 2;
  const int q0 = qt * 128;

  __shared__ __attribute__((aligned(16))) u16 Ks[64 * 128];      // [kv][d]
  __shared__ __attribute__((aligned(16))) u16 Vs[128 * 64];      // [d][kv]
  __shared__ __attribute__((aligned(16))) u16 Ps[4][32 * 64];    // per-wave

  // Q fragments: 2 m-frags x 4 k-steps, from global (rows q0 + wv*32 + mf*16 + lo)
  bf16x8 qf[2][4];
#pragma unroll
  for (int mf = 0; mf < 2; ++mf) {
    const u16* qp = qkv + (size_t)(q0 + wv * 32 + mf * 16 + lo) * 6144 + h * 128;
#pragma unroll
    for (int ks = 0; ks < 4; ++ks)
      qf[mf][ks] = __builtin_bit_cast(bf16x8, *(const u32x4*)(qp + ks * 32 + hi * 8));
  }

  f32x4 acc[2][8];
#pragma unroll
  for (int mf = 0; mf < 2; ++mf)
#pragma unroll
    for (int df = 0; df < 8; ++df) acc[mf][df] = fzero4();
  float m_run[2][4], l_run[2][4];
#pragma unroll
  for (int mf = 0; mf < 2; ++mf)
#pragma unroll
    for (int r = 0; r < 4; ++r) { m_run[mf][r] = -1e30f; l_run[mf][r] = 0.f; }
  const float scale = 0.08838834764831845f;

  // staging map: round r covers kv rows r*16 + (tid>>4), cols (tid&15)*8..+7
  const int srow = tid >> 4;
  const int sd0 = (tid & 15) * 8;
  const int nkt = 2 * qt + 2;

  u32x4 kpre[4], vpre[4];
  {
    const u16* kb = qkv + (size_t)srow * 6144 + 4096 + kvh * 128 + sd0;
#pragma unroll
    for (int r = 0; r < 4; ++r) {
      kpre[r] = *(const u32x4*)(kb + (size_t)r * 16 * 6144);
      vpre[r] = *(const u32x4*)(kb + (size_t)r * 16 * 6144 + 1024);
    }
  }

  for (int kt = 0; kt < nkt; ++kt) {
    __syncthreads();   // previous tiles fully consumed

    // ---- write staged tile (K: b128; V: transposed swizzled u16 scatter)
#pragma unroll
    for (int r = 0; r < 4; ++r) {
      int kv = r * 16 + srow;
      *(u32x4*)&Ks[kv * 128 + (sd0 ^ ((kv & 7) << 3))] = kpre[r];
#pragma unroll
      for (int i = 0; i < 8; ++i) {
        int d = sd0 + i;
        int f = (d & 7) ^ ((d >> 3) & 7);
        u16 val = (u16)(vpre[r][i >> 1] >> (16 * (i & 1)));
        Vs[d * 64 + (kv ^ (f << 3))] = val;
      }
    }

    // ---- issue prefetch for kt+1 (lands under this tile's compute)
    if (kt + 1 < nkt) {
      const u16* kb = qkv + (size_t)((kt + 1) * 64 + srow) * 6144 + 4096 + kvh * 128 + sd0;
#pragma unroll
      for (int r = 0; r < 4; ++r) {
        kpre[r] = *(const u32x4*)(kb + (size_t)r * 16 * 6144);
        vpre[r] = *(const u32x4*)(kb + (size_t)r * 16 * 6144 + 1024);
      }
    }

    __syncthreads();   // tiles visible

    const bool domask = (kt >= 2 * qt);
    const int kvoff = kt * 64 - q0;

#pragma unroll
    for (int mf = 0; mf < 2; ++mf) {
      // ---- S = Q K^T (32 q-rows x 64 kv per wave, this mf: 16 x 64)
      f32x4 s[4];
#pragma unroll
      for (int nf = 0; nf < 4; ++nf) s[nf] = fzero4();
#pragma unroll
      for (int nf = 0; nf < 4; ++nf) {
        int rr = nf * 16 + lo;
#pragma unroll
        for (int ks = 0; ks < 4; ++ks) {
          bf16x8 kf = __builtin_bit_cast(bf16x8,
              *(const u32x4*)&Ks[rr * 128 + ((ks * 32 + hi * 8) ^ ((rr & 7) << 3))]);
          s[nf] = MFMA16(qf[mf][ks], kf, s[nf]);
        }
      }

      // ---- online softmax (rows = mf*16 + hi*4 + r local to wave's 32)
      const int qrow = wv * 32 + mf * 16 + hi * 4;
      float p[4][4];
      float mt[4] = {-1e30f, -1e30f, -1e30f, -1e30f};
#pragma unroll
      for (int nf = 0; nf < 4; ++nf)
#pragma unroll
        for (int r = 0; r < 4; ++r) {
          float v = s[nf][r] * scale;
          if (domask && (kvoff + nf * 16 + lo > qrow + r)) v = -1e30f;
          p[nf][r] = v;
          mt[r] = fmaxf(mt[r], v);
        }
#pragma unroll
      for (int m = 1; m <= 8; m <<= 1)
#pragma unroll
        for (int r = 0; r < 4; ++r)
          mt[r] = fmaxf(mt[r], __shfl_xor(mt[r], m));
      float alpha[4], rs[4];
#pragma unroll
      for (int r = 0; r < 4; ++r) {
        float mn = fmaxf(m_run[mf][r], mt[r]);
        alpha[r] = __expf(m_run[mf][r] - mn);
        m_run[mf][r] = mn;
        rs[r] = 0.f;
      }
#pragma unroll
      for (int nf = 0; nf < 4; ++nf)
#pragma unroll
        for (int r = 0; r < 4; ++r) {
          p[nf][r] = __expf(p[nf][r] - m_run[mf][r]);
          rs[r] += p[nf][r];
        }
#pragma unroll
      for (int m = 1; m <= 8; m <<= 1)
#pragma unroll
        for (int r = 0; r < 4; ++r)
          rs[r] += __shfl_xor(rs[r], m);
#pragma unroll
      for (int r = 0; r < 4; ++r)
        l_run[mf][r] = l_run[mf][r] * alpha[r] + rs[r];
#pragma unroll
      for (int df = 0; df < 8; ++df)
#pragma unroll
        for (int r = 0; r < 4; ++r)
          acc[mf][df][r] *= alpha[r];

      // ---- P -> wave-private LDS (C-frag -> A-frag re-layout)
#pragma unroll
      for (int nf = 0; nf < 4; ++nf)
#pragma unroll
        for (int r = 0; r < 4; ++r) {
          int row = mf * 16 + hi * 4 + r;
          Ps[wv][row * 64 + ((nf * 16 + lo) ^ ((row & 7) << 3))] = f2bf(p[nf][r]);
        }
    }

    // ---- O += P V
    bf16x8 pa[2][2];
#pragma unroll
    for (int mf = 0; mf < 2; ++mf)
#pragma unroll
      for (int ks2 = 0; ks2 < 2; ++ks2) {
        int row = mf * 16 + lo;
        pa[mf][ks2] = __builtin_bit_cast(bf16x8,
            *(const u32x4*)&Ps[wv][row * 64 + ((ks2 * 32 + hi * 8) ^ ((row & 7) << 3))]);
      }
#pragma unroll
    for (int df = 0; df < 8; ++df) {
      bf16x8 vf[2];
#pragma unroll
      for (int ks2 = 0; ks2 < 2; ++ks2) {
        int d = df * 16 + lo;
        int f = (d & 7) ^ ((d >> 3) & 7);
        vf[ks2] = __builtin_bit_cast(bf16x8,
            *(const u32x4*)&Vs[d * 64 + ((ks2 * 32 + hi * 8) ^ (f << 3))]);
      }
#pragma unroll
      for (int mf = 0; mf < 2; ++mf)
#pragma unroll
        for (int ks2 = 0; ks2 < 2; ++ks2)
          acc[mf][df] = MFMA16(pa[mf][ks2], vf[ks2], acc[mf][df]);
    }
  }

  // ---- normalize + write ctx
#pragma unroll
  for (int mf = 0; mf < 2; ++mf)
#pragma unroll
    for (int df = 0; df < 8; ++df)
#pragma unroll
      for (int r = 0; r < 4; ++r) {
        int row = q0 + wv * 32 + mf * 16 + hi * 4 + r;
        int col = h * 128 + df * 16 + lo;
        ctx[(size_t)row * 4096 + col] = f2bf(acc[mf][df][r] / l_run[mf][r]);
      }
}

// ---------------------------------------------------------------------------
extern "C" void kernel_launch(void* const* d_in, const int* in_sizes, int n_in,
                              void* d_out, int out_size, void* d_ws, size_t ws_size,
                              hipStream_t stream) {
  const float* hidden    = (const float*)d_in[0];
  const int* positions   = (const int*)d_in[1];
  const float* w_qkv     = (const float*)d_in[2];
  const float* w_o       = (const float*)d_in[3];

  u16* qkv = (u16*)d_out;
  u16* ctx = (u16*)d_ws;
  float* out = (float*)d_out;

  gemm_kernel<6144, 4096, false, true>
      <<<dim3(48, 16), 256, 0, stream>>>(hidden, w_qkv, qkv);
  rope_kernel<<<dim3(10, 2048), 256, 0, stream>>>(qkv, positions);
  attn_kernel<<<dim3(32, 16), 256, 0, stream>>>(qkv, ctx);
  gemm_kernel<4096, 4096, true, false>
      <<<dim3(32, 16), 256, 0, stream>>>(ctx, w_o, out);
}

// Round 8
// 653.639 us; speedup vs baseline: 1.3848x; 1.3053x over previous
//
#include <hip/hip_runtime.h>
#include <hip/hip_bf16.h>

typedef unsigned short u16;
typedef unsigned int u32;
typedef float f32x4 __attribute__((ext_vector_type(4)));
typedef short bf16x8 __attribute__((ext_vector_type(8)));
typedef u32 u32x4 __attribute__((ext_vector_type(4)));

__device__ __forceinline__ u16 f2bf(float f) {
  u32 x = __builtin_bit_cast(u32, f);
  x += 0x7fffu + ((x >> 16) & 1u);
  return (u16)(x >> 16);
}
__device__ __forceinline__ float bf2f(u16 h) {
  return __builtin_bit_cast(float, (u32)h << 16);
}
__device__ __forceinline__ u32 pk2(float a, float b) {
  return (u32)f2bf(a) | ((u32)f2bf(b) << 16);
}
__device__ __forceinline__ f32x4 fzero4() {
  f32x4 v; v[0] = 0.f; v[1] = 0.f; v[2] = 0.f; v[3] = 0.f; return v;
}
#define MFMA16(a, b, c) __builtin_amdgcn_mfma_f32_16x16x32_bf16(a, b, c, 0, 0, 0)

// async global->LDS, 16B per lane, LDS dest = wave-uniform base + lane*16
__device__ __forceinline__ void llds16(const u16* g, u16* l) {
  __builtin_amdgcn_global_load_lds(
      (const __attribute__((address_space(1))) void*)(const void*)g,
      (__attribute__((address_space(3))) void*)(void*)l, 16, 0, 0);
}

// ---------------------------------------------------------------------------
// Pre-pass 1: f32 -> bf16 elementwise (8/thread)
// ---------------------------------------------------------------------------
__global__ void __launch_bounds__(256)
cvt_bf16_kernel(const float* __restrict__ in, u16* __restrict__ out) {
  const size_t i = (size_t)blockIdx.x * 256 + threadIdx.x;
  const f32x4* p = (const f32x4*)(in + i * 8);
  f32x4 a = p[0], b = p[1];
  u32x4 w;
  w[0] = pk2(a[0], a[1]); w[1] = pk2(a[2], a[3]);
  w[2] = pk2(b[0], b[1]); w[3] = pk2(b[2], b[3]);
  *(u32x4*)(out + i * 8) = w;
}

// ---------------------------------------------------------------------------
// Pre-pass 2: transpose+convert  in f32 [K][N]  ->  out bf16 [N][K]
// 64x64 tile via padded LDS (u32 k-pairs), coalesced on both sides.
// ---------------------------------------------------------------------------
template<int K, int N>
__global__ void __launch_bounds__(256)
transpose_bf16_kernel(const float* __restrict__ in, u16* __restrict__ out) {
  __shared__ u32 T[64][36];   // [n][k-pair], +4 pad words
  const int t = threadIdx.x;
  const int n0 = blockIdx.x * 64, k0 = blockIdx.y * 64;
#pragma unroll
  for (int rr = 0; rr < 2; ++rr) {
    const int kp = rr * 32 + ((t >> 4) << 1);
    const int n4 = (t & 15) * 4;
    f32x4 r0 = *(const f32x4*)&in[(size_t)(k0 + kp) * N + n0 + n4];
    f32x4 r1 = *(const f32x4*)&in[(size_t)(k0 + kp + 1) * N + n0 + n4];
#pragma unroll
    for (int i = 0; i < 4; ++i)
      T[n4 + i][kp >> 1] = pk2(r0[i], r1[i]);
  }
  __syncthreads();
  {
    const int ln = t >> 2, w8 = (t & 3) * 8;
    u32x4 a = *(const u32x4*)&T[ln][w8];
    u32x4 b = *(const u32x4*)&T[ln][w8 + 4];
    u16* o = out + (size_t)(n0 + ln) * K + k0 + w8 * 2;
    *(u32x4*)(o) = a;
    *(u32x4*)(o + 8) = b;
  }
}

// ---------------------------------------------------------------------------
// GEMM (fast path, m97 structure): C[M][N] = A[M][K] x Bt[N][K]^T, all bf16 in.
// 128x128 tile, BK=64, 4 waves (2x2), global_load_lds(16B) -> linear LDS.
// ---------------------------------------------------------------------------
template<int N, int K, bool OUTBF16>
__global__ void __launch_bounds__(256, 4)
gemm_bb_kernel(const u16* __restrict__ A, const u16* __restrict__ Bt,
               void* __restrict__ Cv) {
  const int tid = threadIdx.x;
  const int lane = tid & 63;
  const int lo = lane & 15, hi = lane >> 4;
  const int wv = tid >> 6;
  const int wr = wv >> 1, wc = wv & 1;
  const int bm0 = blockIdx.y * 128, bn0 = blockIdx.x * 128;

  __shared__ __attribute__((aligned(16))) u16 As[128 * 64];
  __shared__ __attribute__((aligned(16))) u16 Bs[128 * 64];

  f32x4 acc[4][4];
#pragma unroll
  for (int i = 0; i < 4; ++i)
#pragma unroll
    for (int j = 0; j < 4; ++j) acc[i][j] = fzero4();

  const int srow = lane >> 3;        // row within 8-row chunk
  const int skoff = (lane & 7) * 8;  // u16 offset within row

  for (int k0 = 0; k0 < K; k0 += 64) {
    __syncthreads();   // previous tile consumed
#pragma unroll
    for (int i = 0; i < 4; ++i) {
      const int chunk = wv * 4 + i;                       // wave-uniform
      const int row = chunk * 8 + srow;
      llds16(A  + (size_t)(bm0 + row) * K + k0 + skoff, &As[chunk * 512]);
      llds16(Bt + (size_t)(bn0 + row) * K + k0 + skoff, &Bs[chunk * 512]);
    }
    __syncthreads();   // (compiler drains vmcnt before barrier)

#pragma unroll
    for (int ks = 0; ks < 2; ++ks) {
      bf16x8 a[4], b[4];
#pragma unroll
      for (int mf = 0; mf < 4; ++mf)
        a[mf] = __builtin_bit_cast(bf16x8,
            *(const u32x4*)&As[(wr * 64 + mf * 16 + lo) * 64 + ks * 32 + hi * 8]);
#pragma unroll
      for (int nf = 0; nf < 4; ++nf)
        b[nf] = __builtin_bit_cast(bf16x8,
            *(const u32x4*)&Bs[(wc * 64 + nf * 16 + lo) * 64 + ks * 32 + hi * 8]);
#pragma unroll
      for (int mf = 0; mf < 4; ++mf)
#pragma unroll
        for (int nf = 0; nf < 4; ++nf)
          acc[mf][nf] = MFMA16(a[mf], b[nf], acc[mf][nf]);
    }
  }

#pragma unroll
  for (int mf = 0; mf < 4; ++mf)
#pragma unroll
    for (int nf = 0; nf < 4; ++nf)
#pragma unroll
      for (int r = 0; r < 4; ++r) {
        int row = bm0 + wr * 64 + mf * 16 + hi * 4 + r;
        int col = bn0 + wc * 64 + nf * 16 + lo;
        if constexpr (OUTBF16)
          ((u16*)Cv)[(size_t)row * N + col] = f2bf(acc[mf][nf][r]);
        else
          ((float*)Cv)[(size_t)row * N + col] = acc[mf][nf][r];
      }
}

// ---------------------------------------------------------------------------
// GEMM (fallback path, round-4 version): B is f32 [K][N], transposed in-kernel.
// ---------------------------------------------------------------------------
template<int N, int K, bool ABF16, bool OUTBF16>
__global__ void __launch_bounds__(256, 2)
gemm_kernel(const void* __restrict__ Av, const float* __restrict__ B,
            void* __restrict__ Cv) {
  const int tid = threadIdx.x;
  const int lane = tid & 63;
  const int lo = lane & 15, hi = lane >> 4;
  const int wv = tid >> 6;
  const int wr = wv >> 1, wc = wv & 1;
  const int bm0 = blockIdx.y * 128, bn0 = blockIdx.x * 128;

  __shared__ __attribute__((aligned(16))) u16 As[128 * 64];
  __shared__ __attribute__((aligned(16))) u16 Bs[128 * 64];

  f32x4 acc[4][4];
#pragma unroll
  for (int i = 0; i < 4; ++i)
#pragma unroll
    for (int j = 0; j < 4; ++j) acc[i][j] = fzero4();

  const int bkp = (tid >> 5) * 2;
  const int bnb = (tid & 31) * 4;

  for (int k0 = 0; k0 < K; k0 += 64) {
    f32x4 brow0[4], brow1[4];
#pragma unroll
    for (int dr = 0; dr < 4; ++dr) {
      int k = dr * 16 + bkp;
      brow0[dr] = *(const f32x4*)&B[(size_t)(k0 + k) * N + bn0 + bnb];
      brow1[dr] = *(const f32x4*)&B[(size_t)(k0 + k + 1) * N + bn0 + bnb];
    }
    f32x4 areg[8];
    u32x4 aregb[4];
    if constexpr (ABF16) {
      const u16* Ab = (const u16*)Av;
#pragma unroll
      for (int rr = 0; rr < 2; ++rr) {
        int row = rr * 64 + (tid >> 2);
        int c16 = (tid & 3) * 16;
        const u16* p = Ab + (size_t)(bm0 + row) * K + k0 + c16;
        aregb[rr * 2 + 0] = *(const u32x4*)(p);
        aregb[rr * 2 + 1] = *(const u32x4*)(p + 8);
      }
    } else {
      const float* Af = (const float*)Av;
#pragma unroll
      for (int rr = 0; rr < 4; ++rr) {
        int row = rr * 32 + (tid >> 3);
        int c8 = (tid & 7) * 8;
        const float* p = Af + (size_t)(bm0 + row) * K + k0 + c8;
        areg[rr * 2 + 0] = *(const f32x4*)(p);
        areg[rr * 2 + 1] = *(const f32x4*)(p + 4);
      }
    }

    __syncthreads();

#pragma unroll
    for (int dr = 0; dr < 4; ++dr) {
      int k = dr * 16 + bkp;
#pragma unroll
      for (int i = 0; i < 4; ++i) {
        int n = bnb + i;
        *(u32*)&Bs[n * 64 + (k ^ ((n & 7) << 3))] = pk2(brow0[dr][i], brow1[dr][i]);
      }
    }
    if constexpr (ABF16) {
#pragma unroll
      for (int rr = 0; rr < 2; ++rr) {
        int row = rr * 64 + (tid >> 2);
        int c16 = (tid & 3) * 16;
        *(u32x4*)&As[row * 64 + ((c16 + 0) ^ ((row & 7) << 3))] = aregb[rr * 2 + 0];
        *(u32x4*)&As[row * 64 + ((c16 + 8) ^ ((row & 7) << 3))] = aregb[rr * 2 + 1];
      }
    } else {
#pragma unroll
      for (int rr = 0; rr < 4; ++rr) {
        int row = rr * 32 + (tid >> 3);
        int c8 = (tid & 7) * 8;
        u32x4 w;
        w[0] = pk2(areg[rr * 2 + 0][0], areg[rr * 2 + 0][1]);
        w[1] = pk2(areg[rr * 2 + 0][2], areg[rr * 2 + 0][3]);
        w[2] = pk2(areg[rr * 2 + 1][0], areg[rr * 2 + 1][1]);
        w[3] = pk2(areg[rr * 2 + 1][2], areg[rr * 2 + 1][3]);
        *(u32x4*)&As[row * 64 + (c8 ^ ((row & 7) << 3))] = w;
      }
    }

    __syncthreads();

#pragma unroll
    for (int ks = 0; ks < 2; ++ks) {
      bf16x8 a[4], b[4];
#pragma unroll
      for (int mf = 0; mf < 4; ++mf) {
        int r = wr * 64 + mf * 16 + lo;
        a[mf] = __builtin_bit_cast(bf16x8,
            *(const u32x4*)&As[r * 64 + ((ks * 32 + hi * 8) ^ ((r & 7) << 3))]);
      }
#pragma unroll
      for (int nf = 0; nf < 4; ++nf) {
        int n = wc * 64 + nf * 16 + lo;
        b[nf] = __builtin_bit_cast(bf16x8,
            *(const u32x4*)&Bs[n * 64 + ((ks * 32 + hi * 8) ^ ((n & 7) << 3))]);
      }
#pragma unroll
      for (int mf = 0; mf < 4; ++mf)
#pragma unroll
        for (int nf = 0; nf < 4; ++nf)
          acc[mf][nf] = MFMA16(a[mf], b[nf], acc[mf][nf]);
    }
  }

#pragma unroll
  for (int mf = 0; mf < 4; ++mf)
#pragma unroll
    for (int nf = 0; nf < 4; ++nf)
#pragma unroll
      for (int r = 0; r < 4; ++r) {
        int row = bm0 + wr * 64 + mf * 16 + hi * 4 + r;
        int col = bn0 + wc * 64 + nf * 16 + lo;
        if constexpr (OUTBF16)
          ((u16*)Cv)[(size_t)row * N + col] = f2bf(acc[mf][nf][r]);
        else
          ((float*)Cv)[(size_t)row * N + col] = acc[mf][nf][r];
      }
}

// ---------------------------------------------------------------------------
// RoPE (unchanged)
// ---------------------------------------------------------------------------
__global__ void __launch_bounds__(256)
rope_kernel(u16* __restrict__ qkv, const int* __restrict__ positions) {
  const int t = blockIdx.y;
  const int pid = blockIdx.x * 256 + threadIdx.x;
  const int head = pid >> 6;
  const int j = pid & 63;
  const int base = (head < 32) ? head * 128 : 4096 + (head - 32) * 128;
  const float pos = (float)positions[t];
  const float freq = exp2f((float)j * (-13.287712379549449f / 64.f));
  float sn, cs;
  sincosf(pos * freq, &sn, &cs);
  u16* p1 = qkv + (size_t)t * 6144 + base + j;
  u16* p2 = p1 + 64;
  const float x1 = bf2f(*p1), x2 = bf2f(*p2);
  *p1 = f2bf(x1 * cs - x2 * sn);
  *p2 = f2bf(x2 * cs + x1 * sn);
}

// ---------------------------------------------------------------------------
// Flash attention (round-4 version): QBLK=128, KVBLK=64, prefetch, LPT.
// ---------------------------------------------------------------------------
__global__ void __launch_bounds__(256, 2)
attn_kernel(const u16* __restrict__ qkv, u16* __restrict__ ctx) {
  const int tid = threadIdx.x;
  const int lane = tid & 63;
  const int lo = lane & 15, hi = lane >> 4;
  const int wv = tid >> 6;
  const int h = blockIdx.x;
  const int qt = 15 - (int)blockIdx.y;
  const int kvh = h >> 2;
  const int q0 = qt * 128;

  __shared__ __attribute__((aligned(16))) u16 Ks[64 * 128];
  __shared__ __attribute__((aligned(16))) u16 Vs[128 * 64];
  __shared__ __attribute__((aligned(16))) u16 Ps[4][32 * 64];

  bf16x8 qf[2][4];
#pragma unroll
  for (int mf = 0; mf < 2; ++mf) {
    const u16* qp = qkv + (size_t)(q0 + wv * 32 + mf * 16 + lo) * 6144 + h * 128;
#pragma unroll
    for (int ks = 0; ks < 4; ++ks)
      qf[mf][ks] = __builtin_bit_cast(bf16x8, *(const u32x4*)(qp + ks * 32 + hi * 8));
  }

  f32x4 acc[2][8];
#pragma unroll
  for (int mf = 0; mf < 2; ++mf)
#pragma unroll
    for (int df = 0; df < 8; ++df) acc[mf][df] = fzero4();
  float m_run[2][4], l_run[2][4];
#pragma unroll
  for (int mf = 0; mf < 2; ++mf)
#pragma unroll
    for (int r = 0; r < 4; ++r) { m_run[mf][r] = -1e30f; l_run[mf][r] = 0.f; }
  const float scale = 0.08838834764831845f;

  const int srow = tid >> 4;
  const int sd0 = (tid & 15) * 8;
  const int nkt = 2 * qt + 2;

  u32x4 kpre[4], vpre[4];
  {
    const u16* kb = qkv + (size_t)srow * 6144 + 4096 + kvh * 128 + sd0;
#pragma unroll
    for (int r = 0; r < 4; ++r) {
      kpre[r] = *(const u32x4*)(kb + (size_t)r * 16 * 6144);
      vpre[r] = *(const u32x4*)(kb + (size_t)r * 16 * 6144 + 1024);
    }
  }

  for (int kt = 0; kt < nkt; ++kt) {
    __syncthreads();

#pragma unroll
    for (int r = 0; r < 4; ++r) {
      int kv = r * 16 + srow;
      *(u32x4*)&Ks[kv * 128 + (sd0 ^ ((kv & 7) << 3))] = kpre[r];
#pragma unroll
      for (int i = 0; i < 8; ++i) {
        int d = sd0 + i;
        int f = (d & 7) ^ ((d >> 3) & 7);
        u16 val = (u16)(vpre[r][i >> 1] >> (16 * (i & 1)));
        Vs[d * 64 + (kv ^ (f << 3))] = val;
      }
    }

    if (kt + 1 < nkt) {
      const u16* kb = qkv + (size_t)((kt + 1) * 64 + srow) * 6144 + 4096 + kvh * 128 + sd0;
#pragma unroll
      for (int r = 0; r < 4; ++r) {
        kpre[r] = *(const u32x4*)(kb + (size_t)r * 16 * 6144);
        vpre[r] = *(const u32x4*)(kb + (size_t)r * 16 * 6144 + 1024);
      }
    }

    __syncthreads();

    const bool domask = (kt >= 2 * qt);
    const int kvoff = kt * 64 - q0;

#pragma unroll
    for (int mf = 0; mf < 2; ++mf) {
      f32x4 s[4];
#pragma unroll
      for (int nf = 0; nf < 4; ++nf) s[nf] = fzero4();
#pragma unroll
      for (int nf = 0; nf < 4; ++nf) {
        int rr = nf * 16 + lo;
#pragma unroll
        for (int ks = 0; ks < 4; ++ks) {
          bf16x8 kf = __builtin_bit_cast(bf16x8,
              *(const u32x4*)&Ks[rr * 128 + ((ks * 32 + hi * 8) ^ ((rr & 7) << 3))]);
          s[nf] = MFMA16(qf[mf][ks], kf, s[nf]);
        }
      }

      const int qrow = wv * 32 + mf * 16 + hi * 4;
      float p[4][4];
      float mt[4] = {-1e30f, -1e30f, -1e30f, -1e30f};
#pragma unroll
      for (int nf = 0; nf < 4; ++nf)
#pragma unroll
        for (int r = 0; r < 4; ++r) {
          float v = s[nf][r] * scale;
          if (domask && (kvoff + nf * 16 + lo > qrow + r)) v = -1e30f;
          p[nf][r] = v;
          mt[r] = fmaxf(mt[r], v);
        }
#pragma unroll
      for (int m = 1; m <= 8; m <<= 1)
#pragma unroll
        for (int r = 0; r < 4; ++r)
          mt[r] = fmaxf(mt[r], __shfl_xor(mt[r], m));
      float alpha[4], rs[4];
#pragma unroll
      for (int r = 0; r < 4; ++r) {
        float mn = fmaxf(m_run[mf][r], mt[r]);
        alpha[r] = __expf(m_run[mf][r] - mn);
        m_run[mf][r] = mn;
        rs[r] = 0.f;
      }
#pragma unroll
      for (int nf = 0; nf < 4; ++nf)
#pragma unroll
        for (int r = 0; r < 4; ++r) {
          p[nf][r] = __expf(p[nf][r] - m_run[mf][r]);
          rs[r] += p[nf][r];
        }
#pragma unroll
      for (int m = 1; m <= 8; m <<= 1)
#pragma unroll
        for (int r = 0; r < 4; ++r)
          rs[r] += __shfl_xor(rs[r], m);
#pragma unroll
      for (int r = 0; r < 4; ++r)
        l_run[mf][r] = l_run[mf][r] * alpha[r] + rs[r];
#pragma unroll
      for (int df = 0; df < 8; ++df)
#pragma unroll
        for (int r = 0; r < 4; ++r)
          acc[mf][df][r] *= alpha[r];

#pragma unroll
      for (int nf = 0; nf < 4; ++nf)
#pragma unroll
        for (int r = 0; r < 4; ++r) {
          int row = mf * 16 + hi * 4 + r;
          Ps[wv][row * 64 + ((nf * 16 + lo) ^ ((row & 7) << 3))] = f2bf(p[nf][r]);
        }
    }

    bf16x8 pa[2][2];
#pragma unroll
    for (int mf = 0; mf < 2; ++mf)
#pragma unroll
      for (int ks2 = 0; ks2 < 2; ++ks2) {
        int row = mf * 16 + lo;
        pa[mf][ks2] = __builtin_bit_cast(bf16x8,
            *(const u32x4*)&Ps[wv][row * 64 + ((ks2 * 32 + hi * 8) ^ ((row & 7) << 3))]);
      }
#pragma unroll
    for (int df = 0; df < 8; ++df) {
      bf16x8 vf[2];
#pragma unroll
      for (int ks2 = 0; ks2 < 2; ++ks2) {
        int d = df * 16 + lo;
        int f = (d & 7) ^ ((d >> 3) & 7);
        vf[ks2] = __builtin_bit_cast(bf16x8,
            *(const u32x4*)&Vs[d * 64 + ((ks2 * 32 + hi * 8) ^ (f << 3))]);
      }
#pragma unroll
      for (int mf = 0; mf < 2; ++mf)
#pragma unroll
        for (int ks2 = 0; ks2 < 2; ++ks2)
          acc[mf][df] = MFMA16(pa[mf][ks2], vf[ks2], acc[mf][df]);
    }
  }

#pragma unroll
  for (int mf = 0; mf < 2; ++mf)
#pragma unroll
    for (int df = 0; df < 8; ++df)
#pragma unroll
      for (int r = 0; r < 4; ++r) {
        int row = q0 + wv * 32 + mf * 16 + hi * 4 + r;
        int col = h * 128 + df * 16 + lo;
        ctx[(size_t)row * 4096 + col] = f2bf(acc[mf][df][r] / l_run[mf][r]);
      }
}

// ---------------------------------------------------------------------------
extern "C" void kernel_launch(void* const* d_in, const int* in_sizes, int n_in,
                              void* d_out, int out_size, void* d_ws, size_t ws_size,
                              hipStream_t stream) {
  const float* hidden    = (const float*)d_in[0];  // [2048][4096]
  const int* positions   = (const int*)d_in[1];
  const float* w_qkv     = (const float*)d_in[2];  // [4096][6144]
  const float* w_o       = (const float*)d_in[3];  // [4096][4096]

  u16* qkv = (u16*)d_out;                 // 2048x6144 bf16 (25.2MB < 33.5MB)
  float* out = (float*)d_out;

  // workspace layout (fast path): ctx | Abf | Bt1 | Bt2
  const size_t SZ_CTX = (size_t)2048 * 4096 * 2;   // 16,777,216
  const size_t SZ_ABF = (size_t)2048 * 4096 * 2;
  const size_t SZ_BT1 = (size_t)6144 * 4096 * 2;   // 50,331,648
  const size_t SZ_BT2 = (size_t)4096 * 4096 * 2;   // 33,554,432
  const size_t NEED = SZ_CTX + SZ_ABF + SZ_BT1 + SZ_BT2;  // 117,440,512

  u16* ctx = (u16*)d_ws;

  if (ws_size >= NEED) {
    u16* Abf = (u16*)((char*)d_ws + SZ_CTX);
    u16* Bt1 = (u16*)((char*)d_ws + SZ_CTX + SZ_ABF);
    u16* Bt2 = (u16*)((char*)d_ws + SZ_CTX + SZ_ABF + SZ_BT1);

    // pre-pass: convert + transpose weights to bf16 [N][K]
    cvt_bf16_kernel<<<4096, 256, 0, stream>>>(hidden, Abf);
    transpose_bf16_kernel<4096, 6144><<<dim3(96, 64), 256, 0, stream>>>(w_qkv, Bt1);
    transpose_bf16_kernel<4096, 4096><<<dim3(64, 64), 256, 0, stream>>>(w_o, Bt2);

    gemm_bb_kernel<6144, 4096, true>
        <<<dim3(48, 16), 256, 0, stream>>>(Abf, Bt1, qkv);
    rope_kernel<<<dim3(10, 2048), 256, 0, stream>>>(qkv, positions);
    attn_kernel<<<dim3(32, 16), 256, 0, stream>>>(qkv, ctx);
    gemm_bb_kernel<4096, 4096, false>
        <<<dim3(32, 16), 256, 0, stream>>>(ctx, Bt2, out);
  } else {
    // fallback: round-4 path (in-kernel f32 B transpose)
    gemm_kernel<6144, 4096, false, true>
        <<<dim3(48, 16), 256, 0, stream>>>(hidden, w_qkv, qkv);
    rope_kernel<<<dim3(10, 2048), 256, 0, stream>>>(qkv, positions);
    attn_kernel<<<dim3(32, 16), 256, 0, stream>>>(qkv, ctx);
    gemm_kernel<4096, 4096, true, false>
        <<<dim3(32, 16), 256, 0, stream>>>(ctx, w_o, out);
  }
}